// Round 10
// baseline (113.714 us; speedup 1.0000x reference)
//
#include <hip/hip_runtime.h>

// HausdorffLoss (average): B=8, N=M=4096, C=128, fp32 in/out.
// R16: barrier-free K-loop via fragment-ordered B. Evidence: all 2-barrier
// staged variants (R10-R15) land 40-54us vs ~14us MFMA floor (~6000cyc/iter
// vs ~1200 pipe demand: vmcnt(0) drain + 8-wave convergence). R9's direct
// global->reg B failed on SCATTERED loads; fix the LAYOUT instead: prep
// stores B in MFMA-fragment order blob[b][colgroup][c][lane] so a wave's
// B-frag load for (group,c) is ONE coalesced global_load_dwordx4 at
// base + g*2048 + c*512 + lane*8. Wave = 64 rows x all 64 groups of its
// panel: per group {4 coalesced loads (dbuf, prefetch-1) + 16 MFMA + ~35
// VALU + 1 LDS atomicMax}. ZERO loop barriers -> compiler emits the
// counted-vmcnt pipeline naturally. L2 traffic 512MB ~ 15us; acc shrinks
// to 16 regs (VGPR ~170). LDS 20KB (colmax_u 16K + bhalf 4K).
// Keeps: e-trick, A frags direct global->reg (swizzled layout unchanged),
// R15 atomic col-max + bhalf-LDS, direct rowpart stores, 3-kernel plan.
// Fill note: harness re-poisons 256MiB ws (~45us/iter) - uncontrollable.
#define B_ 8
#define N_ 4096
#define M_ 4096
#define C_ 128
#define BN_ (B_ * N_)
#define BM_ (B_ * M_)

typedef __attribute__((ext_vector_type(8))) short bf16x8;    // MFMA A/B frag
typedef __attribute__((ext_vector_type(4))) float floatx4;   // MFMA C/D frag
typedef __attribute__((ext_vector_type(8))) unsigned short ushort8;

// fp32 -> bf16 round-to-nearest-even
__device__ __forceinline__ unsigned short f2bf(float x) {
    unsigned int u = __float_as_uint(x);
    u += 0x7FFFu + ((u >> 16) & 1u);
    return (unsigned short)(u >> 16);
}

// monotone float->uint order map (works for mixed signs, no NaN inputs)
__device__ __forceinline__ unsigned fkey(float f) {
    unsigned u = __float_as_uint(f);
    return u ^ (unsigned)(((int)u >> 31) | 0x80000000);
}
__device__ __forceinline__ float funkey(unsigned k) {
    unsigned u = (k & 0x80000000u) ? (k ^ 0x80000000u) : ~k;
    return __uint_as_float(u);
}

// async global->LDS, 16 B per lane; LDS dest = wave-uniform base + lane*16
__device__ __forceinline__ void gl2lds16(const void* g, void* l) {
    __builtin_amdgcn_global_load_lds(
        (const __attribute__((address_space(1))) void*)g,
        (__attribute__((address_space(3))) void*)l, 16, 0, 0);
}

// ---------------------------------------------------------------------------
// Prep. A rows (row < BN): swizzled row-major bfA[row][g ^ (row&15)] (as
// before, matches af direct-load cancellation). B rows: FRAGMENT ORDER:
//   elem = b*M*C + (col>>4)*2048 + (k>>5)*512 + (((k>>3)&3)*16 + (col&15))*8
//        + (k&7)
// so the mfma kernel's (group,c) load is coalesced: base+g*2048+c*512+lane*8.
// Lane g4 holds exactly k = g4*8..g4*8+7 -> cc=g4>>2, quad=g4&3.
// norms[row] = -0.5*||row||^2. Grid = (BN_+BM_)/64 = 1024 blocks.
// ---------------------------------------------------------------------------
__global__ __launch_bounds__(256) void prep_kernel(
    const float* __restrict__ S1, const float* __restrict__ S2,
    float* __restrict__ norms, unsigned short* __restrict__ bfA,
    unsigned short* __restrict__ bfB, float* __restrict__ out) {
    const int lane = threadIdx.x & 63;
    const int w    = threadIdx.x >> 6;
    const int r4   = lane >> 4;
    const int g4   = lane & 15;

    #pragma unroll
    for (int step = 0; step < 4; ++step) {
        const int row = blockIdx.x * 64 + step * 16 + w * 4 + r4;  // 0..65535

        const float* src = (row < BN_) ? S1 + (size_t)row * C_
                                       : S2 + (size_t)(row - BN_) * C_;
        float4 v0 = ((const float4*)src)[g4 * 2];
        float4 v1 = ((const float4*)src)[g4 * 2 + 1];

        float s = v0.x*v0.x + v0.y*v0.y + v0.z*v0.z + v0.w*v0.w
                + v1.x*v1.x + v1.y*v1.y + v1.z*v1.z + v1.w*v1.w;
        s += __shfl_xor(s, 1, 64);
        s += __shfl_xor(s, 2, 64);
        s += __shfl_xor(s, 4, 64);
        s += __shfl_xor(s, 8, 64);

        ushort8 o;
        o[0] = f2bf(v0.x); o[1] = f2bf(v0.y);
        o[2] = f2bf(v0.z); o[3] = f2bf(v0.w);
        o[4] = f2bf(v1.x); o[5] = f2bf(v1.y);
        o[6] = f2bf(v1.z); o[7] = f2bf(v1.w);

        if (row < BN_) {
            unsigned short* dst = bfA + (size_t)row * C_;
            *(ushort8*)&dst[(g4 ^ (row & 15)) * 8] = o;
        } else {
            const int rB   = row - BN_;      // 0..32767
            const int bb   = rB >> 12;       // batch
            const int colb = rB & 4095;      // col within batch
            unsigned short* dst = bfB + (size_t)bb * (M_ * C_)
                                + (size_t)(colb >> 4) * 2048
                                + (g4 >> 2) * 512
                                + (((g4 & 3) * 16) + (colb & 15)) * 8;
            *(ushort8*)dst = o;
        }

        if (g4 == 0) norms[row] = -0.5f * s;
    }
    if (blockIdx.x == 0 && threadIdx.x < B_) out[threadIdx.x] = 0.f;
}

// ---------------------------------------------------------------------------
// Main: grid (N/256, M/1024, B). 4 waves; wave = its 64 rows x all 64
// col-groups of the panel. No LDS staging, no loop barriers.
// ---------------------------------------------------------------------------

// B-fragment load for group g_: 4 coalesced dwordx4 (1 KB each per wave)
#define LOADB(dst_, g_)                                                       \
  do {                                                                        \
    _Pragma("unroll")                                                         \
    for (int c_ = 0; c_ < 4; ++c_)                                            \
        dst_[c_] = *(const bf16x8*)&Bp[(size_t)(g_) * 2048 + c_ * 512 + lane * 8]; \
  } while (0)

// One group's compute on buffer bf_: e-trick acc init, 16 MFMA, epilogue.
#define COMPUTE(bf_, g_)                                                      \
  do {                                                                        \
    const int gg_ = (g_);                                                     \
    const float hb_ = bhalf_lds[gg_ * 16 + lm];                               \
    floatx4 acc_[4];                                                          \
    _Pragma("unroll")                                                         \
    for (int i_ = 0; i_ < 4; ++i_)                                            \
      _Pragma("unroll")                                                       \
      for (int r_ = 0; r_ < 4; ++r_)                                          \
          acc_[i_][r_] = ha[4 * i_ + r_] + hb_;                               \
    _Pragma("unroll")                                                         \
    for (int c_ = 0; c_ < 4; ++c_)                                            \
      _Pragma("unroll")                                                       \
      for (int i_ = 0; i_ < 4; ++i_)                                          \
          acc_[i_] = __builtin_amdgcn_mfma_f32_16x16x32_bf16(                 \
              af[i_][c_], bf_[c_], acc_[i_], 0, 0, 0);                        \
    _Pragma("unroll")                                                         \
    for (int i_ = 0; i_ < 4; ++i_)                                            \
      _Pragma("unroll")                                                       \
      for (int r_ = 0; r_ < 4; ++r_)                                          \
          rv[4 * i_ + r_] = fmaxf(rv[4 * i_ + r_], acc_[i_][r_]);             \
    float t0_ = fmaxf(fmaxf(acc_[0][0], acc_[0][1]),                          \
                      fmaxf(acc_[0][2], acc_[0][3]));                         \
    float t1_ = fmaxf(fmaxf(acc_[1][0], acc_[1][1]),                          \
                      fmaxf(acc_[1][2], acc_[1][3]));                         \
    float t2_ = fmaxf(fmaxf(acc_[2][0], acc_[2][1]),                          \
                      fmaxf(acc_[2][2], acc_[2][3]));                         \
    float t3_ = fmaxf(fmaxf(acc_[3][0], acc_[3][1]),                          \
                      fmaxf(acc_[3][2], acc_[3][3]));                         \
    float cv_ = fmaxf(fmaxf(t0_, t1_), fmaxf(t2_, t3_));                      \
    atomicMax(&colmax_u[gg_ * 16 + lm][quad], fkey(cv_));                     \
  } while (0)

__global__ __launch_bounds__(256, 2) void hausdorff_mfma(
    const unsigned short* __restrict__ Abf, const unsigned short* __restrict__ Bfr,
    const float* __restrict__ ahalf_g, const float* __restrict__ bhalf_g,
    float* __restrict__ rowpart, float* __restrict__ colpart) {

    __shared__ unsigned int colmax_u[1024][4];      // 16 KB keys [col][quad]
    __shared__ float bhalf_lds[1024];               // 4 KB

    const int b     = blockIdx.z;
    const int x     = blockIdx.x;
    const int panel = blockIdx.y;                   // cols panel*1024 ..
    const int row0  = x * 256;
    const int tid   = threadIdx.x;
    const int lane  = tid & 63;
    const int w     = tid >> 6;
    const int lm    = lane & 15;
    const int quad  = lane >> 4;
    const int wrow  = w * 64;                       // wave's 64-row slice

    const unsigned short* Aws = Abf + ((size_t)b * N_ + row0 + wrow) * C_;
    // fragment-ordered B base for this (b, panel): groups g=0..63
    const unsigned short* Bp  = Bfr + (size_t)b * (M_ * C_)
                              + (size_t)panel * 64 * 2048;

    // init colmax keys to 0 (== -inf under the order map)
    {
        uint4 z; z.x = z.y = z.z = z.w = 0u;
        unsigned int* cm = &colmax_u[0][0];
        #pragma unroll
        for (int k = 0; k < 4; ++k)
            *(uint4*)&cm[tid * 16 + k * 4] = z;
    }

    // stage bhalf panel (1024 f32 = 4 KB): 1 gl2lds16 per thread
    gl2lds16(bhalf_g + (size_t)b * M_ + panel * 1024 + w * 256 + lane * 4,
             &bhalf_lds[w * 256]);

    // A fragments: one-time direct global->reg (swizzle cancels: row&15==lm)
    bf16x8 af[4][4];
    #pragma unroll
    for (int i = 0; i < 4; ++i)
        #pragma unroll
        for (int c = 0; c < 4; ++c)
            af[i][c] = *(const bf16x8*)
                &Aws[(16 * i + lm) * 128 + (((c * 4 + quad) ^ lm) * 8)];

    // -0.5*||a||^2 for this lane's 16 rows: wrow + 16i + 4*quad + r
    float ha[16];
    #pragma unroll
    for (int i = 0; i < 4; ++i) {
        float4 t = *(const float4*)&ahalf_g[(size_t)b * N_ + row0 + wrow + 16 * i + 4 * quad];
        ha[4*i+0] = t.x; ha[4*i+1] = t.y; ha[4*i+2] = t.z; ha[4*i+3] = t.w;
    }

    float rv[16];                                   // running e-max per row
    #pragma unroll
    for (int v = 0; v < 16; ++v) rv[v] = -1e30f;

    __syncthreads();   // colmax init + bhalf staged (gl2lds drained)

    // barrier-free group loop: named dbuf regs (rule #20: no runtime index)
    bf16x8 bfrA[4], bfrB[4];
    LOADB(bfrA, 0);
    for (int g = 0; g < 64; g += 2) {
        LOADB(bfrB, g + 1);
        COMPUTE(bfrA, g);
        if (g + 2 < 64) LOADB(bfrA, g + 2);
        COMPUTE(bfrB, g + 1);
    }

    // row maxes: butterfly across the 16 lane-cols; waves own disjoint rows
    #pragma unroll
    for (int s = 1; s < 16; s <<= 1)
        #pragma unroll
        for (int v = 0; v < 16; ++v)
            rv[v] = fmaxf(rv[v], __shfl_xor(rv[v], s, 64));
    if (lm == 0) {
        #pragma unroll
        for (int v = 0; v < 16; ++v)
            rowpart[((size_t)panel * B_ + b) * N_ + row0 + wrow +
                    16 * (v >> 2) + 4 * quad + (v & 3)] = rv[v];
    }

    __syncthreads();   // all colmax atomics done

    // flush col partials: 4 cols/thread, decode keys, float4 store
    {
        const int c0 = tid * 4;
        float cout[4];
        #pragma unroll
        for (int cc = 0; cc < 4; ++cc) {
            uint4 q = *(const uint4*)&colmax_u[c0 + cc][0];
            unsigned k = max(max(q.x, q.y), max(q.z, q.w));
            cout[cc] = funkey(k);
        }
        *(float4*)&colpart[((size_t)x * B_ + b) * M_ + (size_t)panel * 1024 + c0] =
            *(float4*)cout;
    }
}

// ---------------------------------------------------------------------------
// Reduce: 64 blocks (8 per batch). rows: max-e over 4 panel partials;
// cols: max-e over 16 row-block partials; d^2 = max(-2e, 0); sqrt-mean.
// ---------------------------------------------------------------------------
__global__ __launch_bounds__(256) void hausdorff_reduce(
    const float* __restrict__ rowpart, const float* __restrict__ colpart,
    float* __restrict__ out) {
    __shared__ float ws4[4];
    const int b    = blockIdx.x >> 3;
    const int part = blockIdx.x & 7;
    const int base = part * 512;
    float s = 0.f;
    for (int i = base + (int)threadIdx.x; i < base + 512; i += 256) {
        float ra = fmaxf(rowpart[((size_t)0 * B_ + b) * N_ + i],
                         rowpart[((size_t)1 * B_ + b) * N_ + i]);
        float rb = fmaxf(rowpart[((size_t)2 * B_ + b) * N_ + i],
                         rowpart[((size_t)3 * B_ + b) * N_ + i]);
        float rm = fmaxf(ra, rb);
        float ca = -1e30f, cb = -1e30f;
        #pragma unroll
        for (int xx = 0; xx < 16; xx += 2) {
            ca = fmaxf(ca, colpart[((size_t)xx * B_ + b) * M_ + i]);
            cb = fmaxf(cb, colpart[((size_t)(xx + 1) * B_ + b) * M_ + i]);
        }
        float cm = fmaxf(ca, cb);
        s += sqrtf(fmaxf(-2.f * rm, 0.f)) * (1.f / N_)
           + sqrtf(fmaxf(-2.f * cm, 0.f)) * (1.f / M_);
    }
    #pragma unroll
    for (int off = 32; off > 0; off >>= 1) s += __shfl_down(s, off, 64);
    if ((threadIdx.x & 63) == 0) ws4[threadIdx.x >> 6] = s;
    __syncthreads();
    if (threadIdx.x == 0)
        atomicAdd(&out[b], ws4[0] + ws4[1] + ws4[2] + ws4[3]);
}

extern "C" void kernel_launch(void* const* d_in, const int* in_sizes, int n_in,
                              void* d_out, int out_size, void* d_ws, size_t ws_size,
                              hipStream_t stream) {
    const float* s1 = (const float*)d_in[0];
    const float* s2 = (const float*)d_in[1];
    float* out = (float*)d_out;

    // ws: norms(BN+BM f32, pre-scaled -0.5x) | bfA | bfB(frag order) |
    //     rowpart[4][B][N] | colpart[16][B][M]
    float* norms         = (float*)d_ws;
    unsigned short* bfA  = (unsigned short*)(norms + BN_ + BM_);
    unsigned short* bfB  = bfA + (size_t)BN_ * C_;
    float* rowpart       = (float*)(bfB + (size_t)BM_ * C_);
    float* colpart       = rowpart + (size_t)4 * B_ * N_;

    prep_kernel<<<(BN_ + BM_) / 64, 256, 0, stream>>>(
        s1, s2, norms, bfA, bfB, out);

    dim3 grid(N_ / 256, M_ / 1024, B_);
    hausdorff_mfma<<<grid, 256, 0, stream>>>(
        bfA, bfB, norms, norms + BN_, rowpart, colpart);

    hausdorff_reduce<<<B_ * 8, 256, 0, stream>>>(rowpart, colpart, out);
}

// Round 11
// 111.403 us; speedup vs baseline: 1.0207x; 1.0207x over previous
//
#include <hip/hip_runtime.h>

// HausdorffLoss (average): B=8, N=M=4096, C=128, fp32 in/out.
// R17: depth-4 register pipeline in the barrier-free group loop. R16
// (prefetch depth 1) was neutral vs R15: per-group compute (~190cyc/wave,
// ~380/SIMD at 2 waves) is shorter than the 300-600cyc L2/L3 latency of
// fragment loads (panels shared by 16 blocks land on different XCDs ->
// non-local L2), so every group paid an exposed vmcnt wait. Pipe floor is
// ~5-6us (64 groups x {16 MFMA || ~49 VALU}); mfma was ~5x above it.
// Fix: 4 named buffers G0..G3; prologue loads groups 0..3; body computes
// group g then reloads that buffer with g+4 -> prefetch distance 3-4
// groups ~570-760 cyc/wave. VGPR ~196 (B 64 + af 64 + ha/rv/acc 48 +
// misc) < 256 -> no spill (R14's spill was 2 live acc sets, not B bufs).
// Everything else identical to R16 (fragment-ordered B, e-trick, LDS
// atomic col-max, bhalf in LDS, 3-kernel plan).
// Fill note: harness re-poisons 256MiB ws (~45us/iter) - uncontrollable.
#define B_ 8
#define N_ 4096
#define M_ 4096
#define C_ 128
#define BN_ (B_ * N_)
#define BM_ (B_ * M_)

typedef __attribute__((ext_vector_type(8))) short bf16x8;    // MFMA A/B frag
typedef __attribute__((ext_vector_type(4))) float floatx4;   // MFMA C/D frag
typedef __attribute__((ext_vector_type(8))) unsigned short ushort8;

// fp32 -> bf16 round-to-nearest-even
__device__ __forceinline__ unsigned short f2bf(float x) {
    unsigned int u = __float_as_uint(x);
    u += 0x7FFFu + ((u >> 16) & 1u);
    return (unsigned short)(u >> 16);
}

// monotone float->uint order map (works for mixed signs, no NaN inputs)
__device__ __forceinline__ unsigned fkey(float f) {
    unsigned u = __float_as_uint(f);
    return u ^ (unsigned)(((int)u >> 31) | 0x80000000);
}
__device__ __forceinline__ float funkey(unsigned k) {
    unsigned u = (k & 0x80000000u) ? (k ^ 0x80000000u) : ~k;
    return __uint_as_float(u);
}

// async global->LDS, 16 B per lane; LDS dest = wave-uniform base + lane*16
__device__ __forceinline__ void gl2lds16(const void* g, void* l) {
    __builtin_amdgcn_global_load_lds(
        (const __attribute__((address_space(1))) void*)g,
        (__attribute__((address_space(3))) void*)l, 16, 0, 0);
}

// ---------------------------------------------------------------------------
// Prep. A rows (row < BN): swizzled row-major bfA[row][g ^ (row&15)] (matches
// af direct-load cancellation). B rows: FRAGMENT ORDER:
//   elem = b*M*C + (col>>4)*2048 + cquad*512 + (slice*16 + (col&15))*8 + k7
// so the mfma kernel's (group,c) load is coalesced: base+g*2048+c*512+lane*8.
// norms[row] = -0.5*||row||^2. Grid = (BN_+BM_)/64 = 1024 blocks.
// ---------------------------------------------------------------------------
__global__ __launch_bounds__(256) void prep_kernel(
    const float* __restrict__ S1, const float* __restrict__ S2,
    float* __restrict__ norms, unsigned short* __restrict__ bfA,
    unsigned short* __restrict__ bfB, float* __restrict__ out) {
    const int lane = threadIdx.x & 63;
    const int w    = threadIdx.x >> 6;
    const int r4   = lane >> 4;
    const int g4   = lane & 15;

    #pragma unroll
    for (int step = 0; step < 4; ++step) {
        const int row = blockIdx.x * 64 + step * 16 + w * 4 + r4;  // 0..65535

        const float* src = (row < BN_) ? S1 + (size_t)row * C_
                                       : S2 + (size_t)(row - BN_) * C_;
        float4 v0 = ((const float4*)src)[g4 * 2];
        float4 v1 = ((const float4*)src)[g4 * 2 + 1];

        float s = v0.x*v0.x + v0.y*v0.y + v0.z*v0.z + v0.w*v0.w
                + v1.x*v1.x + v1.y*v1.y + v1.z*v1.z + v1.w*v1.w;
        s += __shfl_xor(s, 1, 64);
        s += __shfl_xor(s, 2, 64);
        s += __shfl_xor(s, 4, 64);
        s += __shfl_xor(s, 8, 64);

        ushort8 o;
        o[0] = f2bf(v0.x); o[1] = f2bf(v0.y);
        o[2] = f2bf(v0.z); o[3] = f2bf(v0.w);
        o[4] = f2bf(v1.x); o[5] = f2bf(v1.y);
        o[6] = f2bf(v1.z); o[7] = f2bf(v1.w);

        if (row < BN_) {
            unsigned short* dst = bfA + (size_t)row * C_;
            *(ushort8*)&dst[(g4 ^ (row & 15)) * 8] = o;
        } else {
            const int rB   = row - BN_;      // 0..32767
            const int bb   = rB >> 12;       // batch
            const int colb = rB & 4095;      // col within batch
            unsigned short* dst = bfB + (size_t)bb * (M_ * C_)
                                + (size_t)(colb >> 4) * 2048
                                + (g4 >> 2) * 512
                                + (((g4 & 3) * 16) + (colb & 15)) * 8;
            *(ushort8*)dst = o;
        }

        if (g4 == 0) norms[row] = -0.5f * s;
    }
    if (blockIdx.x == 0 && threadIdx.x < B_) out[threadIdx.x] = 0.f;
}

// ---------------------------------------------------------------------------
// Main: grid (N/256, M/1024, B). 4 waves; wave = its 64 rows x all 64
// col-groups of the panel. No LDS staging, no loop barriers.
// ---------------------------------------------------------------------------

// B-fragment load for group g_: 4 coalesced dwordx4 (1 KB each per wave)
#define LOADB(dst_, g_)                                                       \
  do {                                                                        \
    _Pragma("unroll")                                                         \
    for (int c_ = 0; c_ < 4; ++c_)                                            \
        dst_[c_] = *(const bf16x8*)&Bp[(size_t)(g_) * 2048 + c_ * 512 + lane * 8]; \
  } while (0)

// One group's compute on buffer bf_: e-trick acc init, 16 MFMA, epilogue.
#define COMPUTE(bf_, g_)                                                      \
  do {                                                                        \
    const int gg_ = (g_);                                                     \
    const float hb_ = bhalf_lds[gg_ * 16 + lm];                               \
    floatx4 acc_[4];                                                          \
    _Pragma("unroll")                                                         \
    for (int i_ = 0; i_ < 4; ++i_)                                            \
      _Pragma("unroll")                                                       \
      for (int r_ = 0; r_ < 4; ++r_)                                          \
          acc_[i_][r_] = ha[4 * i_ + r_] + hb_;                               \
    _Pragma("unroll")                                                         \
    for (int c_ = 0; c_ < 4; ++c_)                                            \
      _Pragma("unroll")                                                       \
      for (int i_ = 0; i_ < 4; ++i_)                                          \
          acc_[i_] = __builtin_amdgcn_mfma_f32_16x16x32_bf16(                 \
              af[i_][c_], bf_[c_], acc_[i_], 0, 0, 0);                        \
    _Pragma("unroll")                                                         \
    for (int i_ = 0; i_ < 4; ++i_)                                            \
      _Pragma("unroll")                                                       \
      for (int r_ = 0; r_ < 4; ++r_)                                          \
          rv[4 * i_ + r_] = fmaxf(rv[4 * i_ + r_], acc_[i_][r_]);             \
    float t0_ = fmaxf(fmaxf(acc_[0][0], acc_[0][1]),                          \
                      fmaxf(acc_[0][2], acc_[0][3]));                         \
    float t1_ = fmaxf(fmaxf(acc_[1][0], acc_[1][1]),                          \
                      fmaxf(acc_[1][2], acc_[1][3]));                         \
    float t2_ = fmaxf(fmaxf(acc_[2][0], acc_[2][1]),                          \
                      fmaxf(acc_[2][2], acc_[2][3]));                         \
    float t3_ = fmaxf(fmaxf(acc_[3][0], acc_[3][1]),                          \
                      fmaxf(acc_[3][2], acc_[3][3]));                         \
    float cv_ = fmaxf(fmaxf(t0_, t1_), fmaxf(t2_, t3_));                      \
    atomicMax(&colmax_u[gg_ * 16 + lm][quad], fkey(cv_));                     \
  } while (0)

__global__ __launch_bounds__(256, 2) void hausdorff_mfma(
    const unsigned short* __restrict__ Abf, const unsigned short* __restrict__ Bfr,
    const float* __restrict__ ahalf_g, const float* __restrict__ bhalf_g,
    float* __restrict__ rowpart, float* __restrict__ colpart) {

    __shared__ unsigned int colmax_u[1024][4];      // 16 KB keys [col][quad]
    __shared__ float bhalf_lds[1024];               // 4 KB

    const int b     = blockIdx.z;
    const int x     = blockIdx.x;
    const int panel = blockIdx.y;                   // cols panel*1024 ..
    const int row0  = x * 256;
    const int tid   = threadIdx.x;
    const int lane  = tid & 63;
    const int w     = tid >> 6;
    const int lm    = lane & 15;
    const int quad  = lane >> 4;
    const int wrow  = w * 64;                       // wave's 64-row slice

    const unsigned short* Aws = Abf + ((size_t)b * N_ + row0 + wrow) * C_;
    // fragment-ordered B base for this (b, panel): groups g=0..63
    const unsigned short* Bp  = Bfr + (size_t)b * (M_ * C_)
                              + (size_t)panel * 64 * 2048;

    // init colmax keys to 0 (== -inf under the order map)
    {
        uint4 z; z.x = z.y = z.z = z.w = 0u;
        unsigned int* cm = &colmax_u[0][0];
        #pragma unroll
        for (int k = 0; k < 4; ++k)
            *(uint4*)&cm[tid * 16 + k * 4] = z;
    }

    // stage bhalf panel (1024 f32 = 4 KB): 1 gl2lds16 per thread
    gl2lds16(bhalf_g + (size_t)b * M_ + panel * 1024 + w * 256 + lane * 4,
             &bhalf_lds[w * 256]);

    // A fragments: one-time direct global->reg (swizzle cancels: row&15==lm)
    bf16x8 af[4][4];
    #pragma unroll
    for (int i = 0; i < 4; ++i)
        #pragma unroll
        for (int c = 0; c < 4; ++c)
            af[i][c] = *(const bf16x8*)
                &Aws[(16 * i + lm) * 128 + (((c * 4 + quad) ^ lm) * 8)];

    // -0.5*||a||^2 for this lane's 16 rows: wrow + 16i + 4*quad + r
    float ha[16];
    #pragma unroll
    for (int i = 0; i < 4; ++i) {
        float4 t = *(const float4*)&ahalf_g[(size_t)b * N_ + row0 + wrow + 16 * i + 4 * quad];
        ha[4*i+0] = t.x; ha[4*i+1] = t.y; ha[4*i+2] = t.z; ha[4*i+3] = t.w;
    }

    float rv[16];                                   // running e-max per row
    #pragma unroll
    for (int v = 0; v < 16; ++v) rv[v] = -1e30f;

    __syncthreads();   // colmax init + bhalf staged (gl2lds drained)

    // barrier-free group loop, depth-4 register pipeline (named bufs,
    // rule #20: no runtime indexing). Compute g, then reload that buffer
    // with g+4 -> prefetch distance 3-4 groups (~570-760 cyc/wave).
    bf16x8 G0[4], G1[4], G2[4], G3[4];
    LOADB(G0, 0); LOADB(G1, 1); LOADB(G2, 2); LOADB(G3, 3);
    #pragma unroll
    for (int g = 0; g < 64; g += 4) {
        COMPUTE(G0, g);
        if (g + 4 < 64) LOADB(G0, g + 4);
        COMPUTE(G1, g + 1);
        if (g + 5 < 64) LOADB(G1, g + 5);
        COMPUTE(G2, g + 2);
        if (g + 6 < 64) LOADB(G2, g + 6);
        COMPUTE(G3, g + 3);
        if (g + 7 < 64) LOADB(G3, g + 7);
    }

    // row maxes: butterfly across the 16 lane-cols; waves own disjoint rows
    #pragma unroll
    for (int s = 1; s < 16; s <<= 1)
        #pragma unroll
        for (int v = 0; v < 16; ++v)
            rv[v] = fmaxf(rv[v], __shfl_xor(rv[v], s, 64));
    if (lm == 0) {
        #pragma unroll
        for (int v = 0; v < 16; ++v)
            rowpart[((size_t)panel * B_ + b) * N_ + row0 + wrow +
                    16 * (v >> 2) + 4 * quad + (v & 3)] = rv[v];
    }

    __syncthreads();   // all colmax atomics done

    // flush col partials: 4 cols/thread, decode keys, float4 store
    {
        const int c0 = tid * 4;
        float cout[4];
        #pragma unroll
        for (int cc = 0; cc < 4; ++cc) {
            uint4 q = *(const uint4*)&colmax_u[c0 + cc][0];
            unsigned k = max(max(q.x, q.y), max(q.z, q.w));
            cout[cc] = funkey(k);
        }
        *(float4*)&colpart[((size_t)x * B_ + b) * M_ + (size_t)panel * 1024 + c0] =
            *(float4*)cout;
    }
}

// ---------------------------------------------------------------------------
// Reduce: 64 blocks (8 per batch). rows: max-e over 4 panel partials;
// cols: max-e over 16 row-block partials; d^2 = max(-2e, 0); sqrt-mean.
// ---------------------------------------------------------------------------
__global__ __launch_bounds__(256) void hausdorff_reduce(
    const float* __restrict__ rowpart, const float* __restrict__ colpart,
    float* __restrict__ out) {
    __shared__ float ws4[4];
    const int b    = blockIdx.x >> 3;
    const int part = blockIdx.x & 7;
    const int base = part * 512;
    float s = 0.f;
    for (int i = base + (int)threadIdx.x; i < base + 512; i += 256) {
        float ra = fmaxf(rowpart[((size_t)0 * B_ + b) * N_ + i],
                         rowpart[((size_t)1 * B_ + b) * N_ + i]);
        float rb = fmaxf(rowpart[((size_t)2 * B_ + b) * N_ + i],
                         rowpart[((size_t)3 * B_ + b) * N_ + i]);
        float rm = fmaxf(ra, rb);
        float ca = -1e30f, cb = -1e30f;
        #pragma unroll
        for (int xx = 0; xx < 16; xx += 2) {
            ca = fmaxf(ca, colpart[((size_t)xx * B_ + b) * M_ + i]);
            cb = fmaxf(cb, colpart[((size_t)(xx + 1) * B_ + b) * M_ + i]);
        }
        float cm = fmaxf(ca, cb);
        s += sqrtf(fmaxf(-2.f * rm, 0.f)) * (1.f / N_)
           + sqrtf(fmaxf(-2.f * cm, 0.f)) * (1.f / M_);
    }
    #pragma unroll
    for (int off = 32; off > 0; off >>= 1) s += __shfl_down(s, off, 64);
    if ((threadIdx.x & 63) == 0) ws4[threadIdx.x >> 6] = s;
    __syncthreads();
    if (threadIdx.x == 0)
        atomicAdd(&out[b], ws4[0] + ws4[1] + ws4[2] + ws4[3]);
}

extern "C" void kernel_launch(void* const* d_in, const int* in_sizes, int n_in,
                              void* d_out, int out_size, void* d_ws, size_t ws_size,
                              hipStream_t stream) {
    const float* s1 = (const float*)d_in[0];
    const float* s2 = (const float*)d_in[1];
    float* out = (float*)d_out;

    // ws: norms(BN+BM f32, pre-scaled -0.5x) | bfA | bfB(frag order) |
    //     rowpart[4][B][N] | colpart[16][B][M]
    float* norms         = (float*)d_ws;
    unsigned short* bfA  = (unsigned short*)(norms + BN_ + BM_);
    unsigned short* bfB  = bfA + (size_t)BN_ * C_;
    float* rowpart       = (float*)(bfB + (size_t)BM_ * C_);
    float* colpart       = rowpart + (size_t)4 * B_ * N_;

    prep_kernel<<<(BN_ + BM_) / 64, 256, 0, stream>>>(
        s1, s2, norms, bfA, bfB, out);

    dim3 grid(N_ / 256, M_ / 1024, B_);
    hausdorff_mfma<<<grid, 256, 0, stream>>>(
        bfA, bfB, norms, norms + BN_, rowpart, colpart);

    hausdorff_reduce<<<B_ * 8, 256, 0, stream>>>(rowpart, colpart, out);
}